// Round 1
// baseline (720.895 us; speedup 1.0000x reference)
//
#include <hip/hip_runtime.h>

// Shapes (fixed by the reference):
// B=4, T=64, L=128, D=768, H=12, d=64
#define NB 4
#define NT 64
#define NL 128
#define ND 768
#define NH 12
#define HD 64

// ---------------------------------------------------------------------------
// Kernel 1: K/V projection.  out[r][j] = sum_c edu[r][c] * W[j][c]
// r in [0, 256) (= b*T+t), j in [0, 768).
// grid (12 j-tiles, 4 r-tiles, 2 matrices), 256 threads.
// ---------------------------------------------------------------------------
__global__ __launch_bounds__(256) void proj_kv(
    const float* __restrict__ edu,
    const float* __restrict__ Wk,
    const float* __restrict__ Wv,
    float* __restrict__ kout,
    float* __restrict__ vout)
{
    const int jc  = blockIdx.x;       // j tile (64 wide)
    const int rc  = blockIdx.y;       // r tile (64 tall)
    const int mat = blockIdx.z;       // 0 = K, 1 = V
    const float* W   = (mat == 0) ? Wk : Wv;
    float*       out = (mat == 0) ? kout : vout;
    const int j0 = jc * 64;
    const int r0 = rc * 64;

    __shared__ float edu_s[64][17];   // +1 pad: conflict-free scalar reads
    __shared__ float w_s[16][68];     // transposed W chunk, row = c, 68 = 64+4 pad (16B-aligned)

    const int tid = threadIdx.x;
    const int j4  = tid & 15;         // this thread's 4 j's: j0 + j4*4 + jj
    const int rg  = tid >> 4;         // this thread's 4 r's: r0 + rg*4 + i

    float acc[4][4];
    #pragma unroll
    for (int i = 0; i < 4; i++)
        #pragma unroll
        for (int jj = 0; jj < 4; jj++) acc[i][jj] = 0.f;

    for (int c0 = 0; c0 < ND; c0 += 16) {
        __syncthreads();
        // stage edu chunk [64 r][16 c]
        {
            int idx = tid;
            #pragma unroll
            for (int rep = 0; rep < 4; rep++, idx += 256) {
                int c = idx & 15, r = idx >> 4;
                edu_s[r][c] = edu[(r0 + r) * ND + c0 + c];
            }
        }
        // stage W chunk transposed: w_s[c][j]
        {
            int idx = tid;
            #pragma unroll
            for (int rep = 0; rep < 4; rep++, idx += 256) {
                int c = idx & 15, j = idx >> 4;
                w_s[c][j] = W[(j0 + j) * ND + c0 + c];
            }
        }
        __syncthreads();
        for (int cc = 0; cc < 16; cc++) {
            float4 w4 = *(const float4*)&w_s[cc][j4 * 4];
            #pragma unroll
            for (int i = 0; i < 4; i++) {
                float e = edu_s[rg * 4 + i][cc];
                acc[i][0] += e * w4.x;
                acc[i][1] += e * w4.y;
                acc[i][2] += e * w4.z;
                acc[i][3] += e * w4.w;
            }
        }
    }
    #pragma unroll
    for (int i = 0; i < 4; i++) {
        int r = r0 + rg * 4 + i;
        float4 o = make_float4(acc[i][0], acc[i][1], acc[i][2], acc[i][3]);
        *(float4*)&out[r * ND + j0 + j4 * 4] = o;
    }
}

// ---------------------------------------------------------------------------
// Kernel 2: speaker-segmented inclusive prefix of outer products.
// M[b,t,h,d,e] = sum_{u<=t, spk[b,u]==spk[b,t]} k[b,u,h,d] * v[b,u,h,e]
// grid (H, T, B), 256 threads. Thread owns col e = tid&63, rows d = (tid>>6)*16 .. +15
// ---------------------------------------------------------------------------
__global__ __launch_bounds__(256) void compute_M(
    const float* __restrict__ kin,
    const float* __restrict__ vin,
    const int* __restrict__ spk,
    float* __restrict__ M)
{
    const int h = blockIdx.x, t = blockIdx.y, b = blockIdx.z;

    __shared__ float k_s[64][64];
    __shared__ float v_s[64][64];
    __shared__ int   spk_s[64];

    const int tid = threadIdx.x;
    if (tid < 64) spk_s[tid] = spk[b * NT + tid];

    const int nu = t + 1;
    for (int idx = tid; idx < nu * 64; idx += 256) {
        int u = idx >> 6, c = idx & 63;
        k_s[u][c] = kin[(b * NT + u) * ND + h * HD + c];
        v_s[u][c] = vin[(b * NT + u) * ND + h * HD + c];
    }
    __syncthreads();

    const int e  = tid & 63;
    const int db = (tid >> 6) * 16;
    float acc[16];
    #pragma unroll
    for (int i = 0; i < 16; i++) acc[i] = 0.f;

    const int myspk = spk_s[t];
    for (int u = 0; u <= t; u++) {
        if (spk_s[u] != myspk) continue;   // uniform branch
        float vv = v_s[u][e];
        float4 k0 = *(const float4*)&k_s[u][db + 0];
        float4 k1 = *(const float4*)&k_s[u][db + 4];
        float4 k2 = *(const float4*)&k_s[u][db + 8];
        float4 k3 = *(const float4*)&k_s[u][db + 12];
        acc[0]  += k0.x * vv; acc[1]  += k0.y * vv; acc[2]  += k0.z * vv; acc[3]  += k0.w * vv;
        acc[4]  += k1.x * vv; acc[5]  += k1.y * vv; acc[6]  += k1.z * vv; acc[7]  += k1.w * vv;
        acc[8]  += k2.x * vv; acc[9]  += k2.y * vv; acc[10] += k2.z * vv; acc[11] += k2.w * vv;
        acc[12] += k3.x * vv; acc[13] += k3.y * vv; acc[14] += k3.z * vv; acc[15] += k3.w * vv;
    }

    float* Mp = M + (size_t)(((b * NT + t) * NH + h)) * (HD * HD);
    #pragma unroll
    for (int i = 0; i < 16; i++) Mp[(db + i) * 64 + e] = acc[i];
}

// ---------------------------------------------------------------------------
// Kernel 3: fused q-projection + attention readout + residual.
// Per (b,t,h) block:
//   phase A: q[l][d] = sum_c te[b,t,l,c] * Wq[h*64+d, c]   (tiled GEMM, LDS)
//   phase B: out[b,t,l,h*64+e] = te[b,t,l,h*64+e] + sum_d q[l][d]*M[b,t,h,d,e]
// grid (H, T, B), 256 threads.
// ---------------------------------------------------------------------------
__global__ __launch_bounds__(256) void fused_qa(
    const float* __restrict__ te,
    const float* __restrict__ Wq,
    const float* __restrict__ M,
    float* __restrict__ out)
{
    const int h = blockIdx.x, t = blockIdx.y, b = blockIdx.z;
    const int bt = b * NT + t;

    __shared__ float q_s[128][68];    // 34816 B
    __shared__ float M_s[64][64];     // 16384 B
    __shared__ float te_s[128][17];   //  8704 B
    __shared__ float w_s[16][68];     //  4352 B   (total 64256 B)

    const int tid = threadIdx.x;

    // ---- phase A: q tile [128 l][64 d] ----
    const int d4 = tid & 15;          // 4 d's: d4*4 + dd
    const int lg = tid >> 4;          // 8 l's: lg*8 + i
    float acc[8][4];
    #pragma unroll
    for (int i = 0; i < 8; i++)
        #pragma unroll
        for (int jj = 0; jj < 4; jj++) acc[i][jj] = 0.f;

    const float* tebase = te + (size_t)bt * NL * ND;

    for (int c0 = 0; c0 < ND; c0 += 16) {
        __syncthreads();
        // stage te chunk [128 l][16 c]
        {
            int idx = tid;
            #pragma unroll
            for (int rep = 0; rep < 8; rep++, idx += 256) {
                int c = idx & 15, l = idx >> 4;
                te_s[l][c] = tebase[l * ND + c0 + c];
            }
        }
        // stage Wq chunk transposed: w_s[c][d]
        {
            int idx = tid;
            #pragma unroll
            for (int rep = 0; rep < 4; rep++, idx += 256) {
                int c = idx & 15, d = idx >> 4;
                w_s[c][d] = Wq[(h * HD + d) * ND + c0 + c];
            }
        }
        __syncthreads();
        for (int cc = 0; cc < 16; cc++) {
            float4 w4 = *(const float4*)&w_s[cc][d4 * 4];
            #pragma unroll
            for (int i = 0; i < 8; i++) {
                float e = te_s[lg * 8 + i][cc];
                acc[i][0] += e * w4.x;
                acc[i][1] += e * w4.y;
                acc[i][2] += e * w4.z;
                acc[i][3] += e * w4.w;
            }
        }
    }
    __syncthreads();
    #pragma unroll
    for (int i = 0; i < 8; i++) {
        float4 o = make_float4(acc[i][0], acc[i][1], acc[i][2], acc[i][3]);
        *(float4*)&q_s[lg * 8 + i][d4 * 4] = o;
    }

    // stage M[b,t,h] (4096 floats, coalesced)
    {
        const float* Mp = M + (size_t)((bt * NH) + h) * (HD * HD);
        int idx = tid;
        #pragma unroll
        for (int rep = 0; rep < 16; rep++, idx += 256) {
            int d = idx >> 6, e = idx & 63;
            M_s[d][e] = Mp[d * 64 + e];
        }
    }
    __syncthreads();

    // ---- phase B: a[l][e] = sum_d q[l][d] * M[d][e]; out = te + a ----
    const int e   = tid & 63;
    const int lg2 = tid >> 6;         // 32 l's: lg2*32 + i
    float acc2[32];
    #pragma unroll
    for (int i = 0; i < 32; i++) acc2[i] = 0.f;

    for (int d4b = 0; d4b < 16; d4b++) {
        float m0 = M_s[d4b * 4 + 0][e];
        float m1 = M_s[d4b * 4 + 1][e];
        float m2 = M_s[d4b * 4 + 2][e];
        float m3 = M_s[d4b * 4 + 3][e];
        #pragma unroll
        for (int i = 0; i < 32; i++) {
            float4 q4 = *(const float4*)&q_s[lg2 * 32 + i][d4b * 4];
            acc2[i] += q4.x * m0 + q4.y * m1 + q4.z * m2 + q4.w * m3;
        }
    }

    #pragma unroll
    for (int i = 0; i < 32; i++) {
        int l = lg2 * 32 + i;
        size_t gidx = ((size_t)bt * NL + l) * ND + h * HD + e;
        out[gidx] = te[gidx] + acc2[i];
    }
}

// ---------------------------------------------------------------------------
extern "C" void kernel_launch(void* const* d_in, const int* in_sizes, int n_in,
                              void* d_out, int out_size, void* d_ws, size_t ws_size,
                              hipStream_t stream)
{
    // inputs: 0 input_ids (unused), 1 speaker_ids, 2 token_embeddings,
    //         3 edu_embeddings, 4 Wk, 5 Wv, 6 Wq
    const int*   spk = (const int*)d_in[1];
    const float* te  = (const float*)d_in[2];
    const float* edu = (const float*)d_in[3];
    const float* Wk  = (const float*)d_in[4];
    const float* Wv  = (const float*)d_in[5];
    const float* Wq  = (const float*)d_in[6];
    float* out = (float*)d_out;

    float* ws   = (float*)d_ws;
    float* kbuf = ws;                       // 196608 floats
    float* vbuf = ws + 196608;              // 196608 floats
    float* Mbuf = ws + 393216;              // 12582912 floats  (total ~51.9 MB)

    proj_kv  <<<dim3(12, 4, 2),   256, 0, stream>>>(edu, Wk, Wv, kbuf, vbuf);
    compute_M<<<dim3(NH, NT, NB), 256, 0, stream>>>(kbuf, vbuf, spk, Mbuf);
    fused_qa <<<dim3(NH, NT, NB), 256, 0, stream>>>(te, Wq, Mbuf, out);
}

// Round 2
// 195.251 us; speedup vs baseline: 3.6921x; 3.6921x over previous
//
#include <hip/hip_runtime.h>
#include <hip/hip_bf16.h>

// Shapes (fixed): B=4, T=64, L=128, D=768, H=12, d=64
#define NB 4
#define NT 64
#define NL 128
#define ND 768
#define NH 12
#define HD 64

typedef __attribute__((ext_vector_type(8))) short short8;
typedef __attribute__((ext_vector_type(4))) float f32x4;

static __device__ __forceinline__ unsigned short f2b(float x) {
    __hip_bfloat16 h = __float2bfloat16(x);
    return *reinterpret_cast<unsigned short*>(&h);
}

// ---------------------------------------------------------------------------
// Kernel 1: K/V projection (fp32, unchanged from round 1 — verified).
// ---------------------------------------------------------------------------
__global__ __launch_bounds__(256) void proj_kv(
    const float* __restrict__ edu,
    const float* __restrict__ Wk,
    const float* __restrict__ Wv,
    float* __restrict__ kout,
    float* __restrict__ vout)
{
    const int jc  = blockIdx.x;
    const int rc  = blockIdx.y;
    const int mat = blockIdx.z;
    const float* W   = (mat == 0) ? Wk : Wv;
    float*       out = (mat == 0) ? kout : vout;
    const int j0 = jc * 64;
    const int r0 = rc * 64;

    __shared__ float edu_s[64][17];
    __shared__ float w_s[16][68];

    const int tid = threadIdx.x;
    const int j4  = tid & 15;
    const int rg  = tid >> 4;

    float acc[4][4];
    #pragma unroll
    for (int i = 0; i < 4; i++)
        #pragma unroll
        for (int jj = 0; jj < 4; jj++) acc[i][jj] = 0.f;

    for (int c0 = 0; c0 < ND; c0 += 16) {
        __syncthreads();
        {
            int idx = tid;
            #pragma unroll
            for (int rep = 0; rep < 4; rep++, idx += 256) {
                int c = idx & 15, r = idx >> 4;
                edu_s[r][c] = edu[(r0 + r) * ND + c0 + c];
            }
        }
        {
            int idx = tid;
            #pragma unroll
            for (int rep = 0; rep < 4; rep++, idx += 256) {
                int c = idx & 15, j = idx >> 4;
                w_s[c][j] = W[(j0 + j) * ND + c0 + c];
            }
        }
        __syncthreads();
        for (int cc = 0; cc < 16; cc++) {
            float4 w4 = *(const float4*)&w_s[cc][j4 * 4];
            #pragma unroll
            for (int i = 0; i < 4; i++) {
                float e = edu_s[rg * 4 + i][cc];
                acc[i][0] += e * w4.x;
                acc[i][1] += e * w4.y;
                acc[i][2] += e * w4.z;
                acc[i][3] += e * w4.w;
            }
        }
    }
    #pragma unroll
    for (int i = 0; i < 4; i++) {
        int r = r0 + rg * 4 + i;
        float4 o = make_float4(acc[i][0], acc[i][1], acc[i][2], acc[i][3]);
        *(float4*)&out[r * ND + j0 + j4 * 4] = o;
    }
}

// ---------------------------------------------------------------------------
// Kernel 2: speaker-segmented prefix of outer products, output TRANSPOSED
// bf16:  Mt[b,t,h][e][d] = M[b,t,h,d,e] = sum_{u<=t, spk match} k[u,h,d]*v[u,h,e]
// Thread owns e = tid&63, d-rows db..db+15 -> Mt writes are 16 contiguous bf16.
// ---------------------------------------------------------------------------
__global__ __launch_bounds__(256) void compute_M(
    const float* __restrict__ kin,
    const float* __restrict__ vin,
    const int* __restrict__ spk,
    unsigned short* __restrict__ Mt)
{
    const int h = blockIdx.x, t = blockIdx.y, b = blockIdx.z;

    __shared__ float k_s[64][64];
    __shared__ float v_s[64][64];
    __shared__ int   spk_s[64];

    const int tid = threadIdx.x;
    if (tid < 64) spk_s[tid] = spk[b * NT + tid];

    const int nu = t + 1;
    for (int idx = tid; idx < nu * 64; idx += 256) {
        int u = idx >> 6, c = idx & 63;
        k_s[u][c] = kin[(b * NT + u) * ND + h * HD + c];
        v_s[u][c] = vin[(b * NT + u) * ND + h * HD + c];
    }
    __syncthreads();

    const int e  = tid & 63;
    const int db = (tid >> 6) * 16;
    float acc[16];
    #pragma unroll
    for (int i = 0; i < 16; i++) acc[i] = 0.f;

    const int myspk = spk_s[t];
    for (int u = 0; u <= t; u++) {
        if (spk_s[u] != myspk) continue;
        float vv = v_s[u][e];
        float4 k0 = *(const float4*)&k_s[u][db + 0];
        float4 k1 = *(const float4*)&k_s[u][db + 4];
        float4 k2 = *(const float4*)&k_s[u][db + 8];
        float4 k3 = *(const float4*)&k_s[u][db + 12];
        acc[0]  += k0.x * vv; acc[1]  += k0.y * vv; acc[2]  += k0.z * vv; acc[3]  += k0.w * vv;
        acc[4]  += k1.x * vv; acc[5]  += k1.y * vv; acc[6]  += k1.z * vv; acc[7]  += k1.w * vv;
        acc[8]  += k2.x * vv; acc[9]  += k2.y * vv; acc[10] += k2.z * vv; acc[11] += k2.w * vv;
        acc[12] += k3.x * vv; acc[13] += k3.y * vv; acc[14] += k3.z * vv; acc[15] += k3.w * vv;
    }

    // Mt[((bt*NH+h)*64 + e)*64 + db + i] = acc[i]  (d index = db+i)
    unsigned short* Mp = Mt + ((size_t)((b * NT + t) * NH + h) * HD + e) * HD + db;
    unsigned short tmp[16];
    #pragma unroll
    for (int i = 0; i < 16; i++) tmp[i] = f2b(acc[i]);
    *(short8*)&Mp[0] = *(short8*)&tmp[0];
    *(short8*)&Mp[8] = *(short8*)&tmp[8];
}

// ---------------------------------------------------------------------------
// Kernel 3: fused bf16 MFMA  q^T = Wq_hp @ te^T,  then a = q @ M, residual.
// Block = (head-pair hp, t, b), 256 threads (4 waves, 2x2 subtiles).
//
// GEMM1: C[d][l] (128x128, K=768) = sum_c Wq[hp*128+d][c] * te[l][c]
//   A-frag: Wq_s[d][c] row-major; B-frag: te_s[l][c] row-major (both natural).
//   C lane layout: l = col = lane&15 ; d = (lane>>4)*4 + reg  -> each lane has
//   one token + 4 consecutive d  => packed 8B writes to row-major q_s[l][d].
// GEMM2: a[l][e] (per head, K=64) = sum_d q_s[l][d] * Mt_s[e][d]
// Epilogue: out = te (fp32) + a.
// ---------------------------------------------------------------------------
__global__ __launch_bounds__(256, 3) void fused_qm(
    const float* __restrict__ te,
    const float* __restrict__ Wq,
    const unsigned short* __restrict__ Mt,
    float* __restrict__ out)
{
    const int hp = blockIdx.x, t = blockIdx.y, b = blockIdx.z;
    const int bt = b * NT + t;

    // 53248 B LDS, phase-unioned:
    //  phase 1: te_s [128][72] @0, wq_s [128][72] @9216 (ushort units)
    //  phase 2: q_s [128][136] @0, mt_s [128][72] @17408
    __shared__ __align__(16) unsigned short smem[26624];
    unsigned short* te_s = smem;
    unsigned short* wq_s = smem + 9216;
    unsigned short* q_s  = smem;
    unsigned short* mt_s = smem + 17408;

    const int tid  = threadIdx.x;
    const int lane = tid & 63;
    const int wv   = tid >> 6;
    const int wm   = wv >> 1;      // d-half   (GEMM1)
    const int wn   = wv & 1;       // token-half (GEMM1)
    const int lr   = lane & 15;
    const int lg   = lane >> 4;

    f32x4 acc[4][4];
    #pragma unroll
    for (int i = 0; i < 4; i++)
        #pragma unroll
        for (int j = 0; j < 4; j++) acc[i][j] = (f32x4){0.f, 0.f, 0.f, 0.f};

    const float* teb = te + (size_t)bt * NL * ND;
    const float* wqb = Wq + (size_t)hp * 128 * ND;

    const int scol = (tid & 7) * 8;   // k-offset within 64-chunk
    const int srow = tid >> 3;        // 0..31

    // ---- GEMM1 K-loop ----
    for (int k0 = 0; k0 < ND; k0 += 64) {
        __syncthreads();
        #pragma unroll
        for (int rep = 0; rep < 4; rep++) {
            int r = srow + rep * 32;
            const float* p = teb + r * ND + k0 + scol;
            float4 x = *(const float4*)p;
            float4 y = *(const float4*)(p + 4);
            unsigned short v[8];
            v[0] = f2b(x.x); v[1] = f2b(x.y); v[2] = f2b(x.z); v[3] = f2b(x.w);
            v[4] = f2b(y.x); v[5] = f2b(y.y); v[6] = f2b(y.z); v[7] = f2b(y.w);
            *(short8*)&te_s[r * 72 + scol] = *(short8*)v;

            const float* pw = wqb + r * ND + k0 + scol;
            float4 xw = *(const float4*)pw;
            float4 yw = *(const float4*)(pw + 4);
            unsigned short w[8];
            w[0] = f2b(xw.x); w[1] = f2b(xw.y); w[2] = f2b(xw.z); w[3] = f2b(xw.w);
            w[4] = f2b(yw.x); w[5] = f2b(yw.y); w[6] = f2b(yw.z); w[7] = f2b(yw.w);
            *(short8*)&wq_s[r * 72 + scol] = *(short8*)w;
        }
        __syncthreads();
        #pragma unroll
        for (int k32 = 0; k32 < 2; k32++) {
            const int ko = k32 * 32 + lg * 8;
            short8 af[4], bf[4];
            #pragma unroll
            for (int tm = 0; tm < 4; tm++)
                af[tm] = *(const short8*)&wq_s[(wm * 64 + tm * 16 + lr) * 72 + ko];
            #pragma unroll
            for (int tn = 0; tn < 4; tn++)
                bf[tn] = *(const short8*)&te_s[(wn * 64 + tn * 16 + lr) * 72 + ko];
            #pragma unroll
            for (int tm = 0; tm < 4; tm++)
                #pragma unroll
                for (int tn = 0; tn < 4; tn++)
                    acc[tm][tn] = __builtin_amdgcn_mfma_f32_16x16x32_bf16(
                        af[tm], bf[tn], acc[tm][tn], 0, 0, 0);
        }
    }

    __syncthreads();   // all GEMM1 LDS reads done; buffers re-purposed below

    // ---- transition: C (= q^T) -> row-major bf16 q_s[l][d] via 8B writes ----
    #pragma unroll
    for (int tm = 0; tm < 4; tm++) {
        const int d0 = wm * 64 + tm * 16 + lg * 4;
        #pragma unroll
        for (int tn = 0; tn < 4; tn++) {
            const int ltok = wn * 64 + tn * 16 + lr;
            f32x4 a = acc[tm][tn];
            uint2 wq2;
            wq2.x = (unsigned)f2b(a.x) | ((unsigned)f2b(a.y) << 16);
            wq2.y = (unsigned)f2b(a.z) | ((unsigned)f2b(a.w) << 16);
            *(uint2*)&q_s[ltok * 136 + d0] = wq2;
        }
    }

    // ---- stage Mt for heads hp*2, hp*2+1 (8192 bf16, coalesced) ----
    {
        const unsigned short* mp = Mt + (size_t)(bt * NH + hp * 2) * (HD * HD);
        #pragma unroll
        for (int rep = 0; rep < 4; rep++) {
            int v   = tid + rep * 256;      // 8-elem chunk index, 0..1023
            int row = v >> 3;               // h2*64 + e
            int col = (v & 7) * 8;          // d offset
            *(short8*)&mt_s[row * 72 + col] = *(const short8*)&mp[v * 8];
        }
    }
    __syncthreads();

    // ---- GEMM2: per-wave one head, 64 tokens x 64 e, K=64 ----
    const int h2 = wv & 1;
    const int lh = wv >> 1;
    f32x4 acc2[4][4];
    #pragma unroll
    for (int i = 0; i < 4; i++)
        #pragma unroll
        for (int j = 0; j < 4; j++) acc2[i][j] = (f32x4){0.f, 0.f, 0.f, 0.f};

    #pragma unroll
    for (int k32 = 0; k32 < 2; k32++) {
        const int ko = k32 * 32 + lg * 8;
        short8 af[4], bf[4];
        #pragma unroll
        for (int tm = 0; tm < 4; tm++)
            af[tm] = *(const short8*)&q_s[(lh * 64 + tm * 16 + lr) * 136 + h2 * 64 + ko];
        #pragma unroll
        for (int tn = 0; tn < 4; tn++)
            bf[tn] = *(const short8*)&mt_s[(h2 * 64 + tn * 16 + lr) * 72 + ko];
        #pragma unroll
        for (int tm = 0; tm < 4; tm++)
            #pragma unroll
            for (int tn = 0; tn < 4; tn++)
                acc2[tm][tn] = __builtin_amdgcn_mfma_f32_16x16x32_bf16(
                    af[tm], bf[tn], acc2[tm][tn], 0, 0, 0);
    }

    // ---- epilogue: out = te + a ----
    const float* tb = te  + (size_t)bt * NL * ND;
    float*       ob = out + (size_t)bt * NL * ND;
    #pragma unroll
    for (int tm = 0; tm < 4; tm++) {
        const int l0 = lh * 64 + tm * 16 + lg * 4;
        #pragma unroll
        for (int tn = 0; tn < 4; tn++) {
            const int cg = hp * 128 + h2 * 64 + tn * 16 + lr;
            f32x4 a = acc2[tm][tn];
            #pragma unroll
            for (int r = 0; r < 4; r++) {
                size_t gi = (size_t)(l0 + r) * ND + cg;
                ob[gi] = tb[gi] + a[r];
            }
        }
    }
}

// ---------------------------------------------------------------------------
extern "C" void kernel_launch(void* const* d_in, const int* in_sizes, int n_in,
                              void* d_out, int out_size, void* d_ws, size_t ws_size,
                              hipStream_t stream)
{
    const int*   spk = (const int*)d_in[1];
    const float* te  = (const float*)d_in[2];
    const float* edu = (const float*)d_in[3];
    const float* Wk  = (const float*)d_in[4];
    const float* Wv  = (const float*)d_in[5];
    const float* Wq  = (const float*)d_in[6];
    float* out = (float*)d_out;

    float* ws   = (float*)d_ws;
    float* kbuf = ws;                         // 196608 f32
    float* vbuf = ws + 196608;                // 196608 f32
    unsigned short* Mtbuf = (unsigned short*)(ws + 393216);  // 12.58M bf16

    proj_kv  <<<dim3(12, 4, 2),   256, 0, stream>>>(edu, Wk, Wv, kbuf, vbuf);
    compute_M<<<dim3(NH, NT, NB), 256, 0, stream>>>(kbuf, vbuf, spk, Mtbuf);
    fused_qm <<<dim3(6, NT, NB),  256, 0, stream>>>(te, Wq, Mtbuf, out);
}

// Round 3
// 157.329 us; speedup vs baseline: 4.5821x; 1.2410x over previous
//
#include <hip/hip_runtime.h>
#include <hip/hip_bf16.h>

// Shapes (fixed): B=4, T=64, L=128, D=768, H=12, d=64
#define NB 4
#define NT 64
#define NL 128
#define ND 768
#define NH 12
#define HD 64

typedef __attribute__((ext_vector_type(8))) short short8;
typedef __attribute__((ext_vector_type(4))) float f32x4;

typedef __attribute__((address_space(3))) unsigned int lds_u32;
typedef __attribute__((address_space(1))) const unsigned int glob_u32;

static __device__ __forceinline__ unsigned short f2b(float x) {
    __hip_bfloat16 h = __float2bfloat16(x);
    return *reinterpret_cast<unsigned short*>(&h);
}
static __device__ __forceinline__ float b2f(unsigned short u) {
    unsigned int v = ((unsigned int)u) << 16;
    union { unsigned int i; float f; } c; c.i = v; return c.f;
}
// async global->LDS, 16B per lane; LDS base must be wave-uniform (dest = base + lane*16)
static __device__ __forceinline__ void gl2lds16(const unsigned short* g, unsigned short* l) {
    __builtin_amdgcn_global_load_lds((glob_u32*)g, (lds_u32*)l, 16, 0, 0);
}

#define TE_ELEMS  (NB*NT*NL*ND)            // 25165824
#define WQ_ELEMS  (ND*ND)                  // 589824
#define TE_CHUNKS (TE_ELEMS/8)             // 3145728
#define NCHUNKS   ((TE_ELEMS+WQ_ELEMS)/8)  // 3219456
#define CONV_BLOCKS 2048

// ---------------------------------------------------------------------------
// Kernel 1 (prep): blocks [0,2048) convert te & Wq fp32->bf16 (memory-bound);
// blocks [2048,2144) do the K/V projection (fp32, compute) — overlapped work.
// ---------------------------------------------------------------------------
__global__ __launch_bounds__(256) void prep(
    const float* __restrict__ te, const float* __restrict__ Wq,
    const float* __restrict__ edu, const float* __restrict__ Wk, const float* __restrict__ Wv,
    unsigned short* __restrict__ te_b, unsigned short* __restrict__ wq_b,
    float* __restrict__ kout, float* __restrict__ vout)
{
    const int tid = threadIdx.x;
    if (blockIdx.x < CONV_BLOCKS) {
        for (size_t c = (size_t)blockIdx.x * 256 + tid; c < (size_t)NCHUNKS;
             c += (size_t)CONV_BLOCKS * 256) {
            const float* s; unsigned short* d;
            if (c < TE_CHUNKS) { s = te + c * 8;               d = te_b + c * 8; }
            else               { s = Wq + (c - TE_CHUNKS) * 8; d = wq_b + (c - TE_CHUNKS) * 8; }
            float4 x = *(const float4*)s;
            float4 y = *(const float4*)(s + 4);
            unsigned short v[8];
            v[0] = f2b(x.x); v[1] = f2b(x.y); v[2] = f2b(x.z); v[3] = f2b(x.w);
            v[4] = f2b(y.x); v[5] = f2b(y.y); v[6] = f2b(y.z); v[7] = f2b(y.w);
            *(short8*)d = *(short8*)v;
        }
        return;
    }
    // ---- projection part: pb in [0,96): jc 12 x rc 4 x mat 2 ----
    const int pb  = blockIdx.x - CONV_BLOCKS;
    const int jc  = pb % 12;
    const int rc  = (pb / 12) & 3;
    const int mat = pb / 48;
    const float* W   = (mat == 0) ? Wk : Wv;
    float*       out = (mat == 0) ? kout : vout;
    const int j0 = jc * 64;
    const int r0 = rc * 64;

    __shared__ float edu_s[64][17];
    __shared__ float w_s[16][68];

    const int j4 = tid & 15;
    const int rg = tid >> 4;

    float acc[4][4];
    #pragma unroll
    for (int i = 0; i < 4; i++)
        #pragma unroll
        for (int jj = 0; jj < 4; jj++) acc[i][jj] = 0.f;

    for (int c0 = 0; c0 < ND; c0 += 16) {
        __syncthreads();
        {
            int idx = tid;
            #pragma unroll
            for (int rep = 0; rep < 4; rep++, idx += 256) {
                int c = idx & 15, r = idx >> 4;
                edu_s[r][c] = edu[(r0 + r) * ND + c0 + c];
            }
        }
        {
            int idx = tid;
            #pragma unroll
            for (int rep = 0; rep < 4; rep++, idx += 256) {
                int c = idx & 15, j = idx >> 4;
                w_s[c][j] = W[(j0 + j) * ND + c0 + c];
            }
        }
        __syncthreads();
        for (int cc = 0; cc < 16; cc++) {
            float4 w4 = *(const float4*)&w_s[cc][j4 * 4];
            #pragma unroll
            for (int i = 0; i < 4; i++) {
                float e = edu_s[rg * 4 + i][cc];
                acc[i][0] += e * w4.x;
                acc[i][1] += e * w4.y;
                acc[i][2] += e * w4.z;
                acc[i][3] += e * w4.w;
            }
        }
    }
    #pragma unroll
    for (int i = 0; i < 4; i++) {
        int r = r0 + rg * 4 + i;
        float4 o = make_float4(acc[i][0], acc[i][1], acc[i][2], acc[i][3]);
        *(float4*)&out[r * ND + j0 + j4 * 4] = o;
    }
}

// ---------------------------------------------------------------------------
// Kernel 2: running speaker-bucket prefix scan (O(T) per block).
// grid (H, B, 2): e-half split. bucket[s][e][d] += k[t][d]*v[t][e] at step t,
// then bucket[spk[t]] slice IS M[t] -> written directly (bf16, [e][d] layout).
// k/v staged once; no barriers inside the t-loop.
// ---------------------------------------------------------------------------
__global__ __launch_bounds__(256) void compute_M(
    const float* __restrict__ kin,
    const float* __restrict__ vin,
    const int* __restrict__ spk,
    unsigned short* __restrict__ Mt)
{
    const int h = blockIdx.x, b = blockIdx.y, eh = blockIdx.z;

    __shared__ float bucket[8][32][65];   // [spk][e-local][d], 66560 B, conflict-free
    __shared__ float k_s[64][64];         // [t][d]
    __shared__ float v_s[64][32];         // [t][e-local]
    __shared__ int   spk_s[64];

    const int tid = threadIdx.x;
    {
        float* p = &bucket[0][0][0];
        for (int i = tid; i < 8 * 32 * 65; i += 256) p[i] = 0.f;
    }
    if (tid < 64) spk_s[tid] = spk[b * NT + tid];
    // stage all k, v rows for this (b,h) once (coalesced)
    for (int idx = tid; idx < 64 * 64; idx += 256) {
        int t = idx >> 6, d = idx & 63;
        k_s[t][d] = kin[((size_t)b * NT + t) * ND + h * HD + d];
    }
    for (int idx = tid; idx < 64 * 32; idx += 256) {
        int t = idx >> 5, e = idx & 31;
        v_s[t][e] = vin[((size_t)b * NT + t) * ND + h * HD + eh * 32 + e];
    }
    __syncthreads();

    const int e  = tid & 31;      // local e
    const int dg = tid >> 5;      // 0..7 -> d = dg*8 + j
    for (int t = 0; t < NT; t++) {
        const int s = spk_s[t];
        const float vv = v_s[t][e];
        unsigned short tmp[8];
        #pragma unroll
        for (int j = 0; j < 8; j++) {
            float m = bucket[s][e][dg * 8 + j] + k_s[t][dg * 8 + j] * vv;
            bucket[s][e][dg * 8 + j] = m;
            tmp[j] = f2b(m);
        }
        unsigned short* mp = Mt + (((size_t)(b * NT + t) * NH + h) * HD + eh * 32 + e) * HD + dg * 8;
        *(short8*)mp = *(short8*)tmp;
    }
}

// ---------------------------------------------------------------------------
// Kernel 3: fused bf16 MFMA, all-async staging.
//   GEMM1: q^T[d][l] = Wq_hp @ te^T (K=768), tiles via global_load_lds (bf16).
//   GEMM2: a[l][e] = q @ M per head (K=64), Mt prefetched via global_load_lds.
//   Epilogue: out = bf16(te) + a  (fp32 store).
// XCD swizzle: 6 same-bt blocks land consecutively on one XCD (L2 reuse).
// ---------------------------------------------------------------------------
__global__ __launch_bounds__(256, 3) void fused_qm(
    const unsigned short* __restrict__ te_b,
    const unsigned short* __restrict__ wq_b,
    const unsigned short* __restrict__ Mt,
    float* __restrict__ out)
{
    const int orig = blockIdx.x;
    const int id   = (orig & 7) * 192 + (orig >> 3);   // bijective, 1536 % 8 == 0
    const int hp   = id % 6;
    const int bt   = id / 6;

    // 53248 B LDS, phase-unioned:
    //  phase 1: te_s [128][64] @0, wq_s [128][64] @8192   (linear, gload_lds dest)
    //  phase 2: q_s [128][136] @0;  mt_s [128][64] @17408 (prefetched at start)
    __shared__ __align__(16) unsigned short smem[26624];
    unsigned short* te_s = smem;
    unsigned short* wq_s = smem + 8192;
    unsigned short* q_s  = smem;
    unsigned short* mt_s = smem + 17408;

    const int tid  = threadIdx.x;
    const int lane = tid & 63;
    const int wv   = tid >> 6;
    const int lr   = lane & 15;
    const int lg   = lane >> 4;
    const int wm   = wv >> 1;     // d-half (GEMM1)
    const int wn   = wv & 1;      // token-half (GEMM1)
    const int r8   = lane >> 3;   // staging row within 8-row group
    const int l8   = lane & 7;    // staging 16B chunk

    const unsigned short* teb = te_b + (size_t)bt * NL * ND;
    const unsigned short* wqb = wq_b + (size_t)hp * 128 * ND;

    // ---- prefetch Mt (2 heads, 16 KB) -> mt_s, overlapped with GEMM1 ----
    {
        const unsigned short* mp = Mt + ((size_t)bt * NH + hp * 2) * (HD * HD);
        #pragma unroll
        for (int j = 0; j < 4; j++) {
            const int off = wv * 2048 + j * 512;   // ushort units, 1 KB per call
            gl2lds16(mp + off + lane * 8, mt_s + off);
        }
    }

    f32x4 acc[4][4];
    #pragma unroll
    for (int i = 0; i < 4; i++)
        #pragma unroll
        for (int j = 0; j < 4; j++) acc[i][j] = (f32x4){0.f, 0.f, 0.f, 0.f};

    // ---- GEMM1 K-loop: pure global_load_lds staging, zero VALU ----
    for (int k0 = 0; k0 < ND; k0 += 64) {
        __syncthreads();
        #pragma unroll
        for (int j = 0; j < 4; j++) {
            const int row = wv * 32 + j * 8 + r8;
            gl2lds16(teb + (size_t)row * ND + k0 + l8 * 8, te_s + (wv * 32 + j * 8) * 64);
            gl2lds16(wqb + (size_t)row * ND + k0 + l8 * 8, wq_s + (wv * 32 + j * 8) * 64);
        }
        __syncthreads();   // drains vmcnt -> tiles ready
        #pragma unroll
        for (int k32 = 0; k32 < 2; k32++) {
            const int ko = k32 * 32 + lg * 8;
            short8 af[4], bf[4];
            #pragma unroll
            for (int tm = 0; tm < 4; tm++)
                af[tm] = *(const short8*)&wq_s[(wm * 64 + tm * 16 + lr) * 64 + ko];
            #pragma unroll
            for (int tn = 0; tn < 4; tn++)
                bf[tn] = *(const short8*)&te_s[(wn * 64 + tn * 16 + lr) * 64 + ko];
            #pragma unroll
            for (int tm = 0; tm < 4; tm++)
                #pragma unroll
                for (int tn = 0; tn < 4; tn++)
                    acc[tm][tn] = __builtin_amdgcn_mfma_f32_16x16x32_bf16(
                        af[tm], bf[tn], acc[tm][tn], 0, 0, 0);
        }
    }

    __syncthreads();   // GEMM1 LDS reads done; region re-purposed as q_s

    // ---- q^T C-frags -> row-major bf16 q_s[l][d] (8B packed writes) ----
    #pragma unroll
    for (int tm = 0; tm < 4; tm++) {
        const int d0 = wm * 64 + tm * 16 + lg * 4;
        #pragma unroll
        for (int tn = 0; tn < 4; tn++) {
            const int ltok = wn * 64 + tn * 16 + lr;
            f32x4 a = acc[tm][tn];
            uint2 w2;
            w2.x = (unsigned)f2b(a.x) | ((unsigned)f2b(a.y) << 16);
            w2.y = (unsigned)f2b(a.z) | ((unsigned)f2b(a.w) << 16);
            *(uint2*)&q_s[ltok * 136 + d0] = w2;
        }
    }
    __syncthreads();

    // ---- GEMM2: per-wave one (token-half, head), 64x64, K=64 ----
    const int h2 = wv & 1;
    const int lh = wv >> 1;
    f32x4 acc2[4][4];
    #pragma unroll
    for (int i = 0; i < 4; i++)
        #pragma unroll
        for (int j = 0; j < 4; j++) acc2[i][j] = (f32x4){0.f, 0.f, 0.f, 0.f};

    #pragma unroll
    for (int k32 = 0; k32 < 2; k32++) {
        const int ko = k32 * 32 + lg * 8;
        short8 af[4], bf[4];
        #pragma unroll
        for (int tm = 0; tm < 4; tm++)
            af[tm] = *(const short8*)&q_s[(lh * 64 + tm * 16 + lr) * 136 + h2 * 64 + ko];
        #pragma unroll
        for (int tn = 0; tn < 4; tn++)
            bf[tn] = *(const short8*)&mt_s[(h2 * 64 + tn * 16 + lr) * 64 + ko];
        #pragma unroll
        for (int tm = 0; tm < 4; tm++)
            #pragma unroll
            for (int tn = 0; tn < 4; tn++)
                acc2[tm][tn] = __builtin_amdgcn_mfma_f32_16x16x32_bf16(
                    af[tm], bf[tn], acc2[tm][tn], 0, 0, 0);
    }

    // ---- epilogue: out = bf16(te) + a  (te_b is L2-hot from staging) ----
    const unsigned short* tb = teb;
    float* ob = out + (size_t)bt * NL * ND;
    #pragma unroll
    for (int tm = 0; tm < 4; tm++) {
        const int l0 = lh * 64 + tm * 16 + lg * 4;
        #pragma unroll
        for (int tn = 0; tn < 4; tn++) {
            const int cg = hp * 128 + h2 * 64 + tn * 16 + lr;
            f32x4 a = acc2[tm][tn];
            #pragma unroll
            for (int r = 0; r < 4; r++) {
                size_t gi = (size_t)(l0 + r) * ND + cg;
                ob[gi] = b2f(tb[gi]) + a[r];
            }
        }
    }
}

// ---------------------------------------------------------------------------
extern "C" void kernel_launch(void* const* d_in, const int* in_sizes, int n_in,
                              void* d_out, int out_size, void* d_ws, size_t ws_size,
                              hipStream_t stream)
{
    const int*   spk = (const int*)d_in[1];
    const float* te  = (const float*)d_in[2];
    const float* edu = (const float*)d_in[3];
    const float* Wk  = (const float*)d_in[4];
    const float* Wv  = (const float*)d_in[5];
    const float* Wq  = (const float*)d_in[6];
    float* out = (float*)d_out;

    // workspace layout (78.3 MB total)
    unsigned short* Mtbuf = (unsigned short*)d_ws;            // 12582912 ush (25.2 MB)
    unsigned short* te_bb = Mtbuf + (size_t)12582912;         // 25165824 ush (50.3 MB)
    unsigned short* wq_bb = te_bb + (size_t)25165824;         //   589824 ush (1.2 MB)
    float* kbuf = (float*)(wq_bb + 589824);                   //   196608 f32
    float* vbuf = kbuf + 196608;                              //   196608 f32

    prep     <<<CONV_BLOCKS + 96, 256, 0, stream>>>(te, Wq, edu, Wk, Wv,
                                                    te_bb, wq_bb, kbuf, vbuf);
    compute_M<<<dim3(NH, NB, 2),  256, 0, stream>>>(kbuf, vbuf, spk, Mtbuf);
    fused_qm <<<6 * NT * NB,      256, 0, stream>>>(te_bb, wq_bb, Mtbuf, out);
}

// Round 4
// 116.203 us; speedup vs baseline: 6.2037x; 1.3539x over previous
//
#include <hip/hip_runtime.h>
#include <hip/hip_bf16.h>

// Shapes (fixed): B=4, T=64, L=128, D=768, H=12, d=64
#define NB 4
#define NT 64
#define NL 128
#define ND 768
#define NH 12
#define HD 64

typedef __attribute__((ext_vector_type(8))) short short8;
typedef __attribute__((ext_vector_type(4))) float f32x4;

typedef __attribute__((address_space(3))) unsigned int lds_u32;
typedef __attribute__((address_space(1))) const unsigned int glob_u32;

static __device__ __forceinline__ unsigned short f2b(float x) {
    __hip_bfloat16 h = __float2bfloat16(x);
    return *reinterpret_cast<unsigned short*>(&h);
}
static __device__ __forceinline__ float b2f(unsigned short u) {
    unsigned int v = ((unsigned int)u) << 16;
    union { unsigned int i; float f; } c; c.i = v; return c.f;
}
// async global->LDS, 16B/lane; LDS dest = base + lane*16 (wave-uniform base)
static __device__ __forceinline__ void gl2lds16(const unsigned short* g, unsigned short* l) {
    __builtin_amdgcn_global_load_lds((glob_u32*)g, (lds_u32*)l, 16, 0, 0);
}

// conversion chunk boundaries (8-float chunks), dst = ws + c*8 contiguous
#define TE_C   3145728u   // te:  25165824 elems
#define WQ_C   3219456u   // Wq:    589824
#define EDU_C  3244032u   // edu:   196608
#define WK_C   3317760u   // Wk:    589824
#define NCHUNK 3391488u   // Wv:    589824

// ---------------------------------------------------------------------------
// Kernel 1: streaming fp32 -> bf16 of te, Wq, edu, Wk, Wv (concatenated dst).
// ---------------------------------------------------------------------------
__global__ __launch_bounds__(256) void conv_bf16(
    const float* __restrict__ te, const float* __restrict__ Wq,
    const float* __restrict__ edu, const float* __restrict__ Wk,
    const float* __restrict__ Wv, unsigned short* __restrict__ dst)
{
    for (size_t c = (size_t)blockIdx.x * 256 + threadIdx.x; c < (size_t)NCHUNK;
         c += (size_t)2048 * 256) {
        const float* s;
        if (c < TE_C)       s = te  + c * 8;
        else if (c < WQ_C)  s = Wq  + (c - TE_C)  * 8;
        else if (c < EDU_C) s = edu + (c - WQ_C)  * 8;
        else if (c < WK_C)  s = Wk  + (c - EDU_C) * 8;
        else                s = Wv  + (c - WK_C)  * 8;
        float4 x = *(const float4*)s;
        float4 y = *(const float4*)(s + 4);
        unsigned short v[8];
        v[0] = f2b(x.x); v[1] = f2b(x.y); v[2] = f2b(x.z); v[3] = f2b(x.w);
        v[4] = f2b(y.x); v[5] = f2b(y.y); v[6] = f2b(y.z); v[7] = f2b(y.w);
        *(short8*)(dst + c * 8) = *(short8*)v;
    }
}

// ---------------------------------------------------------------------------
// Kernel 2: fused K/V projection (bf16 MFMA) + speaker-bucket prefix scan.
// grid (H, B, 2 e-halves), 256 threads (4 waves).
// Phase 1: k_s[t][d] (64x64 f32), v_s[t][e] (64x32 f32) via MFMA, K=768.
//   A = W rows (out dim), B = edu rows (t); C row = out dim, col = t.
// Phase 2: running bucket scan -> Mt[b,t,h][e][d] bf16 (O(T), no barriers).
// ---------------------------------------------------------------------------
__global__ __launch_bounds__(256) void kvm(
    const unsigned short* __restrict__ edu_b,
    const unsigned short* __restrict__ wk_b,
    const unsigned short* __restrict__ wv_b,
    const int* __restrict__ spk,
    unsigned short* __restrict__ Mt)
{
    const int h = blockIdx.x, b = blockIdx.y, eh = blockIdx.z;

    __shared__ float bucket[8][32][65];                 // 66560 B, e-stride odd
    __shared__ float k_s[64][68];                       // 17408 B
    __shared__ float v_s[64][36];                       //  9216 B
    __shared__ __align__(16) unsigned short stage[10240]; // edu 4096 | wk 4096 | wv 2048
    __shared__ int spk_s[64];
    unsigned short* edu_s = stage;
    unsigned short* wk_s  = stage + 4096;
    unsigned short* wv_s  = stage + 8192;

    const int tid = threadIdx.x, lane = tid & 63, wvx = tid >> 6;
    const int lr = lane & 15, lg = lane >> 4, r8 = lane >> 3, l8 = lane & 7;

    { float* p = &bucket[0][0][0];
      for (int i = tid; i < 8 * 32 * 65; i += 256) p[i] = 0.f; }
    if (tid < 64) spk_s[tid] = spk[b * NT + tid];

    const unsigned short* edub = edu_b + (size_t)(b * 64) * ND;
    const unsigned short* wkb  = wk_b + (size_t)(h * 64) * ND;
    const unsigned short* wvb  = wv_b + (size_t)(h * 64 + eh * 32) * ND;

    f32x4 acc_k[4], acc_v[2];
    #pragma unroll
    for (int i = 0; i < 4; i++) acc_k[i] = (f32x4){0.f, 0.f, 0.f, 0.f};
    #pragma unroll
    for (int i = 0; i < 2; i++) acc_v[i] = (f32x4){0.f, 0.f, 0.f, 0.f};

    const int sswz = ((l8 ^ r8) * 8);   // pre-swizzled source chunk (ush)

    for (int k0 = 0; k0 < ND; k0 += 64) {
        __syncthreads();
        #pragma unroll
        for (int j = 0; j < 5; j++) {
            const int cid = wvx * 5 + j;   // 0..19, wave-uniform
            const unsigned short* gs; unsigned short* ls;
            if (cid < 8)       { gs = edub + (size_t)(cid * 8 + r8) * ND;        ls = edu_s + cid * 512; }
            else if (cid < 16) { gs = wkb  + (size_t)((cid - 8) * 8 + r8) * ND;  ls = wk_s + (cid - 8) * 512; }
            else               { gs = wvb  + (size_t)((cid - 16) * 8 + r8) * ND; ls = wv_s + (cid - 16) * 512; }
            gl2lds16(gs + k0 + sswz, ls);
        }
        __syncthreads();
        #pragma unroll
        for (int k32 = 0; k32 < 2; k32++) {
            const int cx = (((k32 * 4 + lg) ^ (lr & 7)) * 8); // all rows used have row&7 == lr&7
            short8 eb = *(const short8*)&edu_s[(wvx * 16 + lr) * 64 + cx];
            #pragma unroll
            for (int jb = 0; jb < 4; jb++) {
                short8 ak = *(const short8*)&wk_s[(jb * 16 + lr) * 64 + cx];
                acc_k[jb] = __builtin_amdgcn_mfma_f32_16x16x32_bf16(ak, eb, acc_k[jb], 0, 0, 0);
            }
            #pragma unroll
            for (int jb = 0; jb < 2; jb++) {
                short8 av = *(const short8*)&wv_s[(jb * 16 + lr) * 64 + cx];
                acc_v[jb] = __builtin_amdgcn_mfma_f32_16x16x32_bf16(av, eb, acc_v[jb], 0, 0, 0);
            }
        }
    }

    // write fragments: lane holds col t = wvx*16+lr, rows j0..j0+3 (j0 = jb*16+lg*4)
    {
        const int t = wvx * 16 + lr;
        #pragma unroll
        for (int jb = 0; jb < 4; jb++) *(f32x4*)&k_s[t][jb * 16 + lg * 4] = acc_k[jb];
        #pragma unroll
        for (int jb = 0; jb < 2; jb++) *(f32x4*)&v_s[t][jb * 16 + lg * 4] = acc_v[jb];
    }
    __syncthreads();

    // ---- bucket scan: thread owns (e = tid&31, d-slice dg*8..dg*8+7) ----
    const int e = tid & 31, dg = tid >> 5;
    for (int t = 0; t < NT; t++) {
        const int s = spk_s[t];
        const float vv = v_s[t][e];
        unsigned short tmp[8];
        #pragma unroll
        for (int jj = 0; jj < 8; jj++) {
            float m = bucket[s][e][dg * 8 + jj] + k_s[t][dg * 8 + jj] * vv;
            bucket[s][e][dg * 8 + jj] = m;
            tmp[jj] = f2b(m);
        }
        unsigned short* mpp = Mt + (((size_t)(b * NT + t) * NH + h) * HD + eh * 32 + e) * HD + dg * 8;
        *(short8*)mpp = *(short8*)tmp;
    }
}

// ---------------------------------------------------------------------------
// Kernel 3: fused bf16 MFMA  q^T = Wq_hp @ te^T  (K=768), a = q @ M, residual.
// All staging via global_load_lds with XOR-swizzled source + swizzled reads
// (rule #21: linear dest, inverse-swz source, swz on read).
// ---------------------------------------------------------------------------
__global__ __launch_bounds__(256, 3) void fused_qm(
    const unsigned short* __restrict__ te_b,
    const unsigned short* __restrict__ wq_b,
    const unsigned short* __restrict__ Mt,
    float* __restrict__ out)
{
    const int orig = blockIdx.x;
    const int id   = (orig & 7) * 192 + (orig >> 3);   // bijective XCD swizzle
    const int hp   = id % 6;
    const int bt   = id / 6;

    // phase 1: te_s [128][64] @0, wq_s [128][64] @8192 (ush)
    // phase 2: q_s [128][136] @0; mt_s [128][64] @17408 (prefetched)
    __shared__ __align__(16) unsigned short smem[26624];
    unsigned short* te_s = smem;
    unsigned short* wq_s = smem + 8192;
    unsigned short* q_s  = smem;
    unsigned short* mt_s = smem + 17408;

    const int tid  = threadIdx.x;
    const int lane = tid & 63;
    const int wvx  = tid >> 6;
    const int lr   = lane & 15;
    const int lg   = lane >> 4;
    const int wm   = wvx >> 1;
    const int wn   = wvx & 1;
    const int r8   = lane >> 3;
    const int l8   = lane & 7;
    const int sswz = ((l8 ^ r8) * 8);   // pre-swizzled source chunk (ush)

    const unsigned short* teb = te_b + (size_t)bt * NL * ND;
    const unsigned short* wqb = wq_b + (size_t)hp * 128 * ND;

    // ---- prefetch Mt (2 heads, 16 KB) -> mt_s (rows of 64 ush, swizzled) ----
    {
        const unsigned short* mp = Mt + ((size_t)bt * NH + hp * 2) * (HD * HD);
        #pragma unroll
        for (int j = 0; j < 4; j++) {
            const int off = wvx * 2048 + j * 512;
            gl2lds16(mp + off + r8 * 64 + sswz, mt_s + off);
        }
    }

    f32x4 acc[4][4];
    #pragma unroll
    for (int i = 0; i < 4; i++)
        #pragma unroll
        for (int j = 0; j < 4; j++) acc[i][j] = (f32x4){0.f, 0.f, 0.f, 0.f};

    // ---- GEMM1 K-loop ----
    for (int k0 = 0; k0 < ND; k0 += 64) {
        __syncthreads();
        #pragma unroll
        for (int j = 0; j < 4; j++) {
            const int rbase = wvx * 32 + j * 8;
            gl2lds16(teb + (size_t)(rbase + r8) * ND + k0 + sswz, te_s + rbase * 64);
            gl2lds16(wqb + (size_t)(rbase + r8) * ND + k0 + sswz, wq_s + rbase * 64);
        }
        __syncthreads();
        #pragma unroll
        for (int k32 = 0; k32 < 2; k32++) {
            short8 af[4], bf[4];
            #pragma unroll
            for (int tm = 0; tm < 4; tm++) {
                const int row = wm * 64 + tm * 16 + lr;
                af[tm] = *(const short8*)&wq_s[row * 64 + (((k32 * 4 + lg) ^ (row & 7)) * 8)];
            }
            #pragma unroll
            for (int tn = 0; tn < 4; tn++) {
                const int row = wn * 64 + tn * 16 + lr;
                bf[tn] = *(const short8*)&te_s[row * 64 + (((k32 * 4 + lg) ^ (row & 7)) * 8)];
            }
            #pragma unroll
            for (int tm = 0; tm < 4; tm++)
                #pragma unroll
                for (int tn = 0; tn < 4; tn++)
                    acc[tm][tn] = __builtin_amdgcn_mfma_f32_16x16x32_bf16(
                        af[tm], bf[tn], acc[tm][tn], 0, 0, 0);
        }
    }

    __syncthreads();   // GEMM1 LDS reads done; region re-purposed as q_s

    // ---- q^T C-frags -> row-major bf16 q_s[l][d] (8B packed writes) ----
    #pragma unroll
    for (int tm = 0; tm < 4; tm++) {
        const int d0 = wm * 64 + tm * 16 + lg * 4;
        #pragma unroll
        for (int tn = 0; tn < 4; tn++) {
            const int ltok = wn * 64 + tn * 16 + lr;
            f32x4 a = acc[tm][tn];
            uint2 w2;
            w2.x = (unsigned)f2b(a.x) | ((unsigned)f2b(a.y) << 16);
            w2.y = (unsigned)f2b(a.z) | ((unsigned)f2b(a.w) << 16);
            *(uint2*)&q_s[ltok * 136 + d0] = w2;
        }
    }
    __syncthreads();

    // ---- GEMM2: per-wave one (token-half, head), 64x64, K=64 ----
    const int h2 = wvx & 1;
    const int lh = wvx >> 1;
    f32x4 acc2[4][4];
    #pragma unroll
    for (int i = 0; i < 4; i++)
        #pragma unroll
        for (int j = 0; j < 4; j++) acc2[i][j] = (f32x4){0.f, 0.f, 0.f, 0.f};

    #pragma unroll
    for (int k32 = 0; k32 < 2; k32++) {
        const int ko = k32 * 32 + lg * 8;
        short8 af[4], bf[4];
        #pragma unroll
        for (int tm = 0; tm < 4; tm++)
            af[tm] = *(const short8*)&q_s[(lh * 64 + tm * 16 + lr) * 136 + h2 * 64 + ko];
        #pragma unroll
        for (int tn = 0; tn < 4; tn++) {
            const int row = h2 * 64 + tn * 16 + lr;
            bf[tn] = *(const short8*)&mt_s[row * 64 + (((k32 * 4 + lg) ^ (row & 7)) * 8)];
        }
        #pragma unroll
        for (int tm = 0; tm < 4; tm++)
            #pragma unroll
            for (int tn = 0; tn < 4; tn++)
                acc2[tm][tn] = __builtin_amdgcn_mfma_f32_16x16x32_bf16(
                    af[tm], bf[tn], acc2[tm][tn], 0, 0, 0);
    }

    // ---- epilogue: out = bf16(te) + a ----
    float* ob = out + (size_t)bt * NL * ND;
    #pragma unroll
    for (int tm = 0; tm < 4; tm++) {
        const int l0 = lh * 64 + tm * 16 + lg * 4;
        #pragma unroll
        for (int tn = 0; tn < 4; tn++) {
            const int cg = hp * 128 + h2 * 64 + tn * 16 + lr;
            f32x4 a = acc2[tm][tn];
            #pragma unroll
            for (int r = 0; r < 4; r++) {
                size_t gi = (size_t)(l0 + r) * ND + cg;
                ob[gi] = b2f(teb[gi]) + a[r];
            }
        }
    }
}

// ---------------------------------------------------------------------------
extern "C" void kernel_launch(void* const* d_in, const int* in_sizes, int n_in,
                              void* d_out, int out_size, void* d_ws, size_t ws_size,
                              hipStream_t stream)
{
    const int*   spk = (const int*)d_in[1];
    const float* te  = (const float*)d_in[2];
    const float* edu = (const float*)d_in[3];
    const float* Wk  = (const float*)d_in[4];
    const float* Wv  = (const float*)d_in[5];
    const float* Wq  = (const float*)d_in[6];
    float* out = (float*)d_out;

    // ws layout (ush units), 79.4 MB total:
    unsigned short* bf    = (unsigned short*)d_ws;
    unsigned short* te_bb = bf;                          // 25165824
    unsigned short* wq_bb = bf + 25165824u;              //   589824
    unsigned short* edu_b = bf + 25755648u;              //   196608
    unsigned short* wk_bb = bf + 25952256u;              //   589824
    unsigned short* wv_bb = bf + 26542080u;              //   589824
    unsigned short* Mtbuf = bf + 27131904u;              // 12582912

    conv_bf16<<<2048,            256, 0, stream>>>(te, Wq, edu, Wk, Wv, bf);
    kvm      <<<dim3(NH, NB, 2), 256, 0, stream>>>(edu_b, wk_bb, wv_bb, spk, Mtbuf);
    fused_qm <<<6 * NT * NB,     256, 0, stream>>>(te_bb, wq_bb, Mtbuf, out);
}

// Round 5
// 109.876 us; speedup vs baseline: 6.5610x; 1.0576x over previous
//
#include <hip/hip_runtime.h>
#include <hip/hip_bf16.h>

// Shapes (fixed): B=4, T=64, L=128, D=768, H=12, d=64
#define NB 4
#define NT 64
#define NL 128
#define ND 768
#define NH 12
#define HD 64

typedef __attribute__((ext_vector_type(8))) short short8;
typedef __attribute__((ext_vector_type(4))) float f32x4;

typedef __attribute__((address_space(3))) unsigned int lds_u32;
typedef __attribute__((address_space(1))) const unsigned int glob_u32;

static __device__ __forceinline__ unsigned short f2b(float x) {
    __hip_bfloat16 h = __float2bfloat16(x);
    return *reinterpret_cast<unsigned short*>(&h);
}
// async global->LDS, 16B/lane; LDS dest = base + lane*16 (wave-uniform base)
static __device__ __forceinline__ void gl2lds16(const void* g, void* l) {
    __builtin_amdgcn_global_load_lds((glob_u32*)g, (lds_u32*)l, 16, 0, 0);
}
// pack 2 f32 -> 2 bf16 (truncation) in one v_perm_b32: low16 = bf(lo), high16 = bf(hi)
static __device__ __forceinline__ unsigned pkbf(float lo, float hi) {
    union { float f; unsigned u; } a, b; a.f = lo; b.f = hi;
    return __builtin_amdgcn_perm(b.u, a.u, 0x07060302u);
}

// conversion chunk boundaries (8-float chunks): Wq | edu | Wk | Wv contiguous
#define WQ_C   73728u
#define EDU_C  98304u
#define WK_C   172032u
#define NCHUNK 245760u

// ---------------------------------------------------------------------------
// Kernel 1: streaming fp32 -> bf16 of Wq, edu, Wk, Wv only (~8 MB, ~2 us).
// te is NOT converted any more — fused_qm stages fp32 te directly.
// ---------------------------------------------------------------------------
__global__ __launch_bounds__(256) void conv_bf16(
    const float* __restrict__ Wq, const float* __restrict__ edu,
    const float* __restrict__ Wk, const float* __restrict__ Wv,
    unsigned short* __restrict__ dst)
{
    size_t c = (size_t)blockIdx.x * 256 + threadIdx.x;
    if (c >= NCHUNK) return;
    const float* s;
    if (c < WQ_C)       s = Wq  + c * 8;
    else if (c < EDU_C) s = edu + (c - WQ_C)  * 8;
    else if (c < WK_C)  s = Wk  + (c - EDU_C) * 8;
    else                s = Wv  + (c - WK_C)  * 8;
    float4 x = *(const float4*)s;
    float4 y = *(const float4*)(s + 4);
    unsigned short v[8];
    v[0] = f2b(x.x); v[1] = f2b(x.y); v[2] = f2b(x.z); v[3] = f2b(x.w);
    v[4] = f2b(y.x); v[5] = f2b(y.y); v[6] = f2b(y.z); v[7] = f2b(y.w);
    *(short8*)(dst + c * 8) = *(short8*)v;
}

// ---------------------------------------------------------------------------
// Kernel 2: fused K/V projection (bf16 MFMA) + speaker-bucket prefix scan.
// (unchanged from round 4 — verified)
// ---------------------------------------------------------------------------
__global__ __launch_bounds__(256) void kvm(
    const unsigned short* __restrict__ edu_b,
    const unsigned short* __restrict__ wk_b,
    const unsigned short* __restrict__ wv_b,
    const int* __restrict__ spk,
    unsigned short* __restrict__ Mt)
{
    const int h = blockIdx.x, b = blockIdx.y, eh = blockIdx.z;

    __shared__ float bucket[8][32][65];
    __shared__ float k_s[64][68];
    __shared__ float v_s[64][36];
    __shared__ __align__(16) unsigned short stage[10240];
    __shared__ int spk_s[64];
    unsigned short* edu_s = stage;
    unsigned short* wk_s  = stage + 4096;
    unsigned short* wv_s  = stage + 8192;

    const int tid = threadIdx.x, lane = tid & 63, wvx = tid >> 6;
    const int lr = lane & 15, lg = lane >> 4, r8 = lane >> 3, l8 = lane & 7;

    { float* p = &bucket[0][0][0];
      for (int i = tid; i < 8 * 32 * 65; i += 256) p[i] = 0.f; }
    if (tid < 64) spk_s[tid] = spk[b * NT + tid];

    const unsigned short* edub = edu_b + (size_t)(b * 64) * ND;
    const unsigned short* wkb  = wk_b + (size_t)(h * 64) * ND;
    const unsigned short* wvb  = wv_b + (size_t)(h * 64 + eh * 32) * ND;

    f32x4 acc_k[4], acc_v[2];
    #pragma unroll
    for (int i = 0; i < 4; i++) acc_k[i] = (f32x4){0.f, 0.f, 0.f, 0.f};
    #pragma unroll
    for (int i = 0; i < 2; i++) acc_v[i] = (f32x4){0.f, 0.f, 0.f, 0.f};

    const int sswz = ((l8 ^ r8) * 8);

    for (int k0 = 0; k0 < ND; k0 += 64) {
        __syncthreads();
        #pragma unroll
        for (int j = 0; j < 5; j++) {
            const int cid = wvx * 5 + j;
            const unsigned short* gs; unsigned short* ls;
            if (cid < 8)       { gs = edub + (size_t)(cid * 8 + r8) * ND;        ls = edu_s + cid * 512; }
            else if (cid < 16) { gs = wkb  + (size_t)((cid - 8) * 8 + r8) * ND;  ls = wk_s + (cid - 8) * 512; }
            else               { gs = wvb  + (size_t)((cid - 16) * 8 + r8) * ND; ls = wv_s + (cid - 16) * 512; }
            gl2lds16(gs + k0 + sswz, ls);
        }
        __syncthreads();
        #pragma unroll
        for (int k32 = 0; k32 < 2; k32++) {
            const int cx = (((k32 * 4 + lg) ^ (lr & 7)) * 8);
            short8 eb = *(const short8*)&edu_s[(wvx * 16 + lr) * 64 + cx];
            #pragma unroll
            for (int jb = 0; jb < 4; jb++) {
                short8 ak = *(const short8*)&wk_s[(jb * 16 + lr) * 64 + cx];
                acc_k[jb] = __builtin_amdgcn_mfma_f32_16x16x32_bf16(ak, eb, acc_k[jb], 0, 0, 0);
            }
            #pragma unroll
            for (int jb = 0; jb < 2; jb++) {
                short8 av = *(const short8*)&wv_s[(jb * 16 + lr) * 64 + cx];
                acc_v[jb] = __builtin_amdgcn_mfma_f32_16x16x32_bf16(av, eb, acc_v[jb], 0, 0, 0);
            }
        }
    }

    {
        const int t = wvx * 16 + lr;
        #pragma unroll
        for (int jb = 0; jb < 4; jb++) *(f32x4*)&k_s[t][jb * 16 + lg * 4] = acc_k[jb];
        #pragma unroll
        for (int jb = 0; jb < 2; jb++) *(f32x4*)&v_s[t][jb * 16 + lg * 4] = acc_v[jb];
    }
    __syncthreads();

    const int e = tid & 31, dg = tid >> 5;
    for (int t = 0; t < NT; t++) {
        const int s = spk_s[t];
        const float vv = v_s[t][e];
        unsigned short tmp[8];
        #pragma unroll
        for (int jj = 0; jj < 8; jj++) {
            float m = bucket[s][e][dg * 8 + jj] + k_s[t][dg * 8 + jj] * vv;
            bucket[s][e][dg * 8 + jj] = m;
            tmp[jj] = f2b(m);
        }
        unsigned short* mpp = Mt + (((size_t)(b * NT + t) * NH + h) * HD + eh * 32 + e) * HD + dg * 8;
        *(short8*)mpp = *(short8*)tmp;
    }
}

// ---------------------------------------------------------------------------
// Kernel 3: fused bf16 MFMA  q^T = Wq_hp @ te^T (K=768), a = q @ M, residual.
// te staged as FP32 via global_load_lds (16B-chunk XOR swizzle: chunk ^= row&15);
// bf16 B-fragments built at read time with v_perm truncation (2 elems/inst).
// wq/Mt stay bf16 (pre-converted), 8-ush-chunk swizzle (chunk ^= row&7).
// ---------------------------------------------------------------------------
__global__ __launch_bounds__(256, 2) void fused_qm(
    const float* __restrict__ te,
    const unsigned short* __restrict__ wq_b,
    const unsigned short* __restrict__ Mt,
    float* __restrict__ out)
{
    const int orig = blockIdx.x;
    const int id   = (orig & 7) * 192 + (orig >> 3);   // bijective XCD swizzle
    const int hp   = id % 6;
    const int bt   = id / 6;

    // 64 KB LDS:
    //  phase 1: wq_s ush[128][64] @byte 0; te_s f32[128][64] @16384; mt_s @49152
    //  phase 2: q_s ush[128][136] @byte 0 (overlaps wq_s/te_s only)
    __shared__ __align__(16) unsigned short smem[32768];
    unsigned short* wq_s = smem;                    // [128][64] ush
    float*          te_s = (float*)(smem + 8192);   // [128][64] f32
    unsigned short* mt_s = smem + 24576;            // [128][64] ush
    unsigned short* q_s  = smem;                    // phase 2

    const int tid  = threadIdx.x;
    const int lane = tid & 63;
    const int wvx  = tid >> 6;
    const int lr   = lane & 15;
    const int lg   = lane >> 4;
    const int wm   = wvx >> 1;
    const int wn   = wvx & 1;
    const int r8   = lane >> 3;
    const int l8   = lane & 7;

    const float*          teb = te + (size_t)bt * NL * ND;
    const unsigned short* wqb = wq_b + (size_t)hp * 128 * ND;

    // ---- prefetch Mt (2 heads, 16 KB) -> mt_s, rows of 64 ush, swz chunk^row&7
    {
        const unsigned short* mp = Mt + ((size_t)bt * NH + hp * 2) * (HD * HD);
        #pragma unroll
        for (int j = 0; j < 4; j++) {
            const int off = wvx * 2048 + j * 512;
            gl2lds16(mp + off + r8 * 64 + (l8 ^ r8) * 8, mt_s + off);
        }
    }

    f32x4 acc[4][4];
    #pragma unroll
    for (int i = 0; i < 4; i++)
        #pragma unroll
        for (int j = 0; j < 4; j++) acc[i][j] = (f32x4){0.f, 0.f, 0.f, 0.f};

    // ---- GEMM1 K-loop ----
    for (int k0 = 0; k0 < ND; k0 += 64) {
        __syncthreads();
        // wq (bf16): 4 calls/wave, 8 rows each
        #pragma unroll
        for (int j = 0; j < 4; j++) {
            const int rbase = wvx * 32 + j * 8;
            gl2lds16(wqb + (size_t)(rbase + r8) * ND + k0 + (l8 ^ r8) * 8,
                     wq_s + rbase * 64);
        }
        // te (fp32): 8 calls/wave, 4 rows each; source col chunk pre-swizzled
        #pragma unroll
        for (int j = 0; j < 8; j++) {
            const int rbase = wvx * 32 + j * 4;
            const int row   = rbase + (lane >> 4);
            const int c     = (lane & 15) ^ (row & 15);
            gl2lds16(teb + (size_t)row * ND + k0 + c * 4, te_s + rbase * 64);
        }
        __syncthreads();
        #pragma unroll
        for (int k32 = 0; k32 < 2; k32++) {
            short8 af[4], bf[4];
            #pragma unroll
            for (int tm = 0; tm < 4; tm++) {
                const int row = wm * 64 + tm * 16 + lr;
                af[tm] = *(const short8*)&wq_s[row * 64 + (((k32 * 4 + lg) ^ (lr & 7)) * 8)];
            }
            #pragma unroll
            for (int tn = 0; tn < 4; tn++) {
                const int row = wn * 64 + tn * 16 + lr;
                const int cg  = k32 * 8 + lg * 2;
                f32x4 x = *(const f32x4*)&te_s[row * 64 + ((cg ^ lr) * 4)];
                f32x4 y = *(const f32x4*)&te_s[row * 64 + (((cg + 1) ^ lr) * 4)];
                union { short8 s; unsigned u[4]; } bb;
                bb.u[0] = pkbf(x.x, x.y);
                bb.u[1] = pkbf(x.z, x.w);
                bb.u[2] = pkbf(y.x, y.y);
                bb.u[3] = pkbf(y.z, y.w);
                bf[tn] = bb.s;
            }
            #pragma unroll
            for (int tm = 0; tm < 4; tm++)
                #pragma unroll
                for (int tn = 0; tn < 4; tn++)
                    acc[tm][tn] = __builtin_amdgcn_mfma_f32_16x16x32_bf16(
                        af[tm], bf[tn], acc[tm][tn], 0, 0, 0);
        }
    }

    __syncthreads();   // GEMM1 LDS reads done; region re-purposed as q_s

    // ---- q^T C-frags -> row-major bf16 q_s[l][d] (8B packed writes) ----
    #pragma unroll
    for (int tm = 0; tm < 4; tm++) {
        const int d0 = wm * 64 + tm * 16 + lg * 4;
        #pragma unroll
        for (int tn = 0; tn < 4; tn++) {
            const int ltok = wn * 64 + tn * 16 + lr;
            f32x4 a = acc[tm][tn];
            uint2 w2;
            w2.x = pkbf(a.x, a.y);
            w2.y = pkbf(a.z, a.w);
            *(uint2*)&q_s[ltok * 136 + d0] = w2;
        }
    }
    __syncthreads();

    // ---- GEMM2: per-wave one (token-half, head), 64x64, K=64 ----
    const int h2 = wvx & 1;
    const int lh = wvx >> 1;
    f32x4 acc2[4][4];
    #pragma unroll
    for (int i = 0; i < 4; i++)
        #pragma unroll
        for (int j = 0; j < 4; j++) acc2[i][j] = (f32x4){0.f, 0.f, 0.f, 0.f};

    #pragma unroll
    for (int k32 = 0; k32 < 2; k32++) {
        const int ko = k32 * 32 + lg * 8;
        short8 af[4], bf[4];
        #pragma unroll
        for (int tm = 0; tm < 4; tm++)
            af[tm] = *(const short8*)&q_s[(lh * 64 + tm * 16 + lr) * 136 + h2 * 64 + ko];
        #pragma unroll
        for (int tn = 0; tn < 4; tn++) {
            const int row = h2 * 64 + tn * 16 + lr;
            bf[tn] = *(const short8*)&mt_s[row * 64 + (((k32 * 4 + lg) ^ (lr & 7)) * 8)];
        }
        #pragma unroll
        for (int tm = 0; tm < 4; tm++)
            #pragma unroll
            for (int tn = 0; tn < 4; tn++)
                acc2[tm][tn] = __builtin_amdgcn_mfma_f32_16x16x32_bf16(
                    af[tm], bf[tn], acc2[tm][tn], 0, 0, 0);
    }

    // ---- epilogue: out = fp32 te + a (te tile is L2-hot from staging) ----
    float* ob = out + (size_t)bt * NL * ND;
    #pragma unroll
    for (int tm = 0; tm < 4; tm++) {
        const int l0 = lh * 64 + tm * 16 + lg * 4;
        #pragma unroll
        for (int tn = 0; tn < 4; tn++) {
            const int cg = hp * 128 + h2 * 64 + tn * 16 + lr;
            f32x4 a = acc2[tm][tn];
            #pragma unroll
            for (int r = 0; r < 4; r++) {
                size_t gi = (size_t)(l0 + r) * ND + cg;
                ob[gi] = teb[gi] + a[r];
            }
        }
    }
}

// ---------------------------------------------------------------------------
extern "C" void kernel_launch(void* const* d_in, const int* in_sizes, int n_in,
                              void* d_out, int out_size, void* d_ws, size_t ws_size,
                              hipStream_t stream)
{
    const int*   spk = (const int*)d_in[1];
    const float* te  = (const float*)d_in[2];
    const float* edu = (const float*)d_in[3];
    const float* Wk  = (const float*)d_in[4];
    const float* Wv  = (const float*)d_in[5];
    const float* Wq  = (const float*)d_in[6];
    float* out = (float*)d_out;

    // ws layout (ush units), ~29 MB total:
    unsigned short* bf    = (unsigned short*)d_ws;
    unsigned short* wq_bb = bf;                 //   589824
    unsigned short* edu_b = bf + 589824u;       //   196608
    unsigned short* wk_bb = bf + 786432u;       //   589824
    unsigned short* wv_bb = bf + 1376256u;      //   589824
    unsigned short* Mtbuf = bf + 1966080u;      // 12582912

    conv_bf16<<<960,             256, 0, stream>>>(Wq, edu, Wk, Wv, bf);
    kvm      <<<dim3(NH, NB, 2), 256, 0, stream>>>(edu_b, wk_bb, wv_bb, spk, Mtbuf);
    fused_qm <<<6 * NT * NB,     256, 0, stream>>>(te, wq_bb, Mtbuf, out);
}